// Round 6
// baseline (144.407 us; speedup 1.0000x reference)
//
#include <hip/hip_runtime.h>
#include <float.h>
#include <math.h>
#include <stdint.h>

// VQ-VAE VectorQuantizer — round 8: pre-packed z B-fragments.
//
// z_e: (32, 256, 32, 32) fp32, weight: (1024, 256) fp32
// outputs concat: quantized_st (8388608) + loss (1) + perplexity (1)
//
// Round-7 ablation: vq_dist alone (no phase 2) = 57 us -> the whole wall is
// z-fragment assembly + MFMA sweep. The one never-removed component is the
// per-element frag assembly (256 strided scalar loads + 256 f2bf per lane,
// 4x redundant per block). Round 8 adds vq_zpack: one streaming pass that
// writes z in MFMA B-fragment layout (bf16, 1 KB frag blocks, same f2bf),
// staged in the OUT buffer (16 MB scratch; scatter overwrites it later in
// stream order). vq_dist's phase A becomes 32 coalesced b128 loads/wave.
//
// score[k][n] = wsq[k] - 2*w_k.z_n  via  mfma_f32_16x16x32_bf16:
//   A (M=16 codes)  = -2*w  (bf16, A-frag order, streamed from L2)
//   B (N=16 z vecs) =  z    (bf16, PRE-PACKED frag blocks, b128 loads)
//   C init          =  wsq[k]
//
// frag block (fb, cc) = 1 KB: lane l (n=l&15, quad=l>>4) holds 8 shorts
//   j=0..7 -> z[b][c=cc*32+quad*8+j][hw=t2*16+n],  fb = b*64 + t2.
//
// ws layout (bytes): [0,4096) wsq f32 | [4096,8192) counts u32
//                    [8192,8196) loss_sum f32
//                    [16384, 540672) cbfrag bf16 (512 KB)
//                    [540672, 671744) fidx i32 (128 KB)
// out buffer: first 16 MB doubles as zfrag scratch (overwritten by scatter).

#define NB   32
#define NC   256
#define NHW  1024
#define NK   1024
#define NELEM (NB*NC*NHW)   // 8388608

typedef __attribute__((ext_vector_type(8))) short bf16x8;   // 8 bf16 = 4 VGPRs
typedef __attribute__((ext_vector_type(4))) float f32x4;

__device__ __forceinline__ unsigned short f2bf(float f) {   // RTN fp32->bf16
    unsigned u = __float_as_uint(f);
    u += 0x7FFFu + ((u >> 16) & 1u);
    return (unsigned short)(u >> 16);
}

// ---------------- K1: prep — pack A-frags (-2w bf16) + wsq + zero accums ---
__global__ __launch_bounds__(256) void vq_prep(const float* __restrict__ w,
                                               unsigned short* __restrict__ cb,
                                               float* __restrict__ wsq,
                                               unsigned int* __restrict__ counts,
                                               float* __restrict__ loss_sum) {
    __shared__ float swsq[4][16];
    const int t   = blockIdx.x;          // code tile 0..63 (16 codes each)
    const int tid = threadIdx.x;
    float sq = 0.f;
#pragma unroll
    for (int rep = 0; rep < 2; ++rep) {
        const int p = tid + rep * 256;   // 0..511
        const int cc = p >> 6, l = p & 63;
        const int n = l & 15, quad = l >> 4;
        const float* src = w + (t * 16 + n) * NC + cc * 32 + quad * 8;
        const float4 f0 = *(const float4*)src;
        const float4 f1 = *(const float4*)(src + 4);
        union { unsigned short u[8]; uint4 v; } pk;
        pk.u[0] = f2bf(-2.f * f0.x); pk.u[1] = f2bf(-2.f * f0.y);
        pk.u[2] = f2bf(-2.f * f0.z); pk.u[3] = f2bf(-2.f * f0.w);
        pk.u[4] = f2bf(-2.f * f1.x); pk.u[5] = f2bf(-2.f * f1.y);
        pk.u[6] = f2bf(-2.f * f1.z); pk.u[7] = f2bf(-2.f * f1.w);
        *(uint4*)(cb + (size_t)t * 4096 + cc * 512 + l * 8) = pk.v;
        sq = fmaf(f0.x, f0.x, sq); sq = fmaf(f0.y, f0.y, sq);
        sq = fmaf(f0.z, f0.z, sq); sq = fmaf(f0.w, f0.w, sq);
        sq = fmaf(f1.x, f1.x, sq); sq = fmaf(f1.y, f1.y, sq);
        sq = fmaf(f1.z, f1.z, sq); sq = fmaf(f1.w, f1.w, sq);
    }
    sq += __shfl_xor(sq, 16, 64);
    sq += __shfl_xor(sq, 32, 64);
    const int wv = tid >> 6, lane = tid & 63;
    if (lane < 16) swsq[wv][lane] = sq;
    __syncthreads();
    if (tid < 16)
        wsq[t * 16 + tid] = swsq[0][tid] + swsq[1][tid] + swsq[2][tid] + swsq[3][tid];
    if (t == 0) {
        for (int i = tid; i < NK; i += 256) counts[i] = 0u;
        if (tid == 0) loss_sum[0] = 0.f;
    }
}

// ---------------- K1b: zpack — z -> bf16 B-fragment blocks ----------------
// grid 512 x 256 (4 waves). Block: (b = bid>>4, 64-hw slab hw0=(bid&15)*64).
// Coalesced float4 z loads -> LDS fp32 tile -> frag assembly -> 1 KB-coalesced
// frag-block stores. Same f2bf as before -> bit-identical fragments.
__global__ __launch_bounds__(256, 2) void vq_zpack(const float* __restrict__ z,
                                                   unsigned short* __restrict__ zf) {
    __shared__ float zt[256][66];                 // 67,584 B; pad 66 (2-way max)
    const int tid  = threadIdx.x;
    const int wv   = tid >> 6;
    const int lane = tid & 63;
    const int n    = lane & 15;
    const int quad = lane >> 4;
    const int bid  = blockIdx.x;
    const int b    = bid >> 4;
    const int hw0  = (bid & 15) << 6;

    const float* zb = z + (size_t)b * (NC * NHW);

    // coalesced load: 16 lanes x float4 = 256 B per c-row, 4 rows per instr
    {
        const int hw4   = (tid & 15) * 4;
        const int cbase = tid >> 4;
#pragma unroll
        for (int p = 0; p < 16; ++p) {
            const int c = cbase + p * 16;
            const float4 v = *(const float4*)(zb + (size_t)c * NHW + hw0 + hw4);
            *(float2*)(&zt[c][hw4])     = make_float2(v.x, v.y);
            *(float2*)(&zt[c][hw4 + 2]) = make_float2(v.z, v.w);
        }
    }
    __syncthreads();

    // assemble: wave wv owns 16-hw subtile t2 = hw0/16 + wv
    const size_t fb = (size_t)b * 64 + (hw0 >> 4) + wv;
    unsigned short* dst0 = zf + fb * 4096;        // 8 cc-blocks x 512 shorts
#pragma unroll
    for (int cc = 0; cc < 8; ++cc) {
        union { unsigned short u[8]; uint4 v; } pk;
#pragma unroll
        for (int j = 0; j < 8; ++j)
            pk.u[j] = f2bf(zt[cc * 32 + quad * 8 + j][wv * 16 + n]);
        *(uint4*)(dst0 + cc * 512 + lane * 8) = pk.v;   // 1 KB contiguous/wave
    }
}

// ---------------- K2: dist — MFMA argmin -> fidx + counts ------------------
// grid 512 x 256 (4 waves). Block: 64 z vecs. Wave wv owns code quarter
// [wv*256, wv*256+256). Phase A is now 32 coalesced b128 loads per wave.
__global__ __launch_bounds__(256, 2) void vq_dist(const unsigned short* __restrict__ zf,
                                                  const float* __restrict__ wsq,
                                                  const unsigned short* __restrict__ cb,
                                                  unsigned int* __restrict__ counts,
                                                  int* __restrict__ gfidx) {
    __shared__ float sval[4][64];
    __shared__ int   sidx[4][64];

    const int tid  = threadIdx.x;
    const int wv   = tid >> 6;            // code quarter 0..3
    const int lane = tid & 63;
    const int quad = lane >> 4;
    const int bid  = blockIdx.x;
    const int b    = bid >> 4;            // batch image
    const int hw0  = (bid & 15) << 6;     // block's 64-row hw origin

    // ---- Phase A: load pre-packed B-fragments (32 x b128, coalesced) ------
    const unsigned short* zf0 = zf + ((size_t)b * 64 + (hw0 >> 4)) * 4096 + lane * 8;
    bf16x8 bfr[4][8];
#pragma unroll
    for (int nt = 0; nt < 4; ++nt)
#pragma unroll
        for (int cc = 0; cc < 8; ++cc)
            bfr[nt][cc] = *(const bf16x8*)(zf0 + (size_t)(nt * 8 + cc) * 512);

    // ---- Main loop: wave sweeps its 16 code tiles straight from L2 --------
    float bv[4] = {FLT_MAX, FLT_MAX, FLT_MAX, FLT_MAX};
    int   bi[4] = {0, 0, 0, 0};
    const unsigned short* ap0 = cb + (size_t)(wv * 16) * 4096 + lane * 8;

    for (int mt = 0; mt < 16; ++mt) {
        const int kt = wv * 256 + mt * 16;
        const unsigned short* ap = ap0 + (size_t)mt * 4096;
        const f32x4 w4 = *(const f32x4*)(wsq + kt + quad * 4);
        f32x4 acc[4];
#pragma unroll
        for (int nt = 0; nt < 4; ++nt) acc[nt] = w4;
#pragma unroll
        for (int cc = 0; cc < 8; ++cc) {
            const bf16x8 af = *(const bf16x8*)(ap + cc * 512);
            acc[0] = __builtin_amdgcn_mfma_f32_16x16x32_bf16(af, bfr[0][cc], acc[0], 0, 0, 0);
            acc[1] = __builtin_amdgcn_mfma_f32_16x16x32_bf16(af, bfr[1][cc], acc[1], 0, 0, 0);
            acc[2] = __builtin_amdgcn_mfma_f32_16x16x32_bf16(af, bfr[2][cc], acc[2], 0, 0, 0);
            acc[3] = __builtin_amdgcn_mfma_f32_16x16x32_bf16(af, bfr[3][cc], acc[3], 0, 0, 0);
        }
#pragma unroll
        for (int nt = 0; nt < 4; ++nt) {
#pragma unroll
            for (int r = 0; r < 4; ++r) {
                const float v = acc[nt][r];
                if (v < bv[nt]) { bv[nt] = v; bi[nt] = kt + quad * 4 + r; }
            }
        }
    }

    // ---- cross-quad argmin (lanes n, n+16, n+32, n+48) --------------------
#pragma unroll
    for (int nt = 0; nt < 4; ++nt) {
#pragma unroll
        for (int off = 16; off <= 32; off <<= 1) {
            const float ov = __shfl_xor(bv[nt], off, 64);
            const int   ok = __shfl_xor(bi[nt], off, 64);
            if (ov < bv[nt] || (ov == bv[nt] && ok < bi[nt])) { bv[nt] = ov; bi[nt] = ok; }
        }
    }
    const int n16 = lane & 15;
    if (lane < 16) {
#pragma unroll
        for (int nt = 0; nt < 4; ++nt) {
            sval[wv][nt * 16 + n16] = bv[nt];
            sidx[wv][nt * 16 + n16] = bi[nt];
        }
    }
    __syncthreads();

    // ---- cross-wave argmin over the 4 code quarters -> global fidx --------
    if (tid < 64) {
        float bestv = sval[0][tid];
        int   besti = sidx[0][tid];
#pragma unroll
        for (int q = 1; q < 4; ++q) {
            const float v = sval[q][tid];
            const int   k = sidx[q][tid];
            if (v < bestv || (v == bestv && k < besti)) { bestv = v; besti = k; }
        }
        gfidx[b * NHW + hw0 + tid] = besti;
        atomicAdd(&counts[besti], 1u);
    }
}

// ---------------- K3: scatter — gather w rows, write out, loss -------------
// grid 1024 = 32 b x 32 c-groups; 256 thr. Thread owns one float4 of
// consecutive hw across 8 c-rows: fully-contiguous 1 KB wave instructions.
__global__ __launch_bounds__(256, 4) void vq_scatter(const float* __restrict__ z,
                                                     const float* __restrict__ w,
                                                     const int* __restrict__ gfidx,
                                                     float* __restrict__ loss_sum,
                                                     float* __restrict__ out) {
    __shared__ float lred[4];
    const int tid = threadIdx.x;
    const int bid = blockIdx.x;
    const int b   = bid >> 5;             // batch image
    const int c0  = (bid & 31) << 3;      // 8 c-rows
    const int hw4 = tid << 2;             // thread's 4 consecutive hw

    const int4 k4 = *(const int4*)(gfidx + b * NHW + hw4);
    const float* zb = z   + (size_t)b * (NC * NHW);
    float*       ob = out + (size_t)b * (NC * NHW);

    float lsum = 0.f;
#pragma unroll
    for (int i = 0; i < 8; ++i) {
        const int c = c0 + i;
        const float4 zq = *(const float4*)(zb + (size_t)c * NHW + hw4);
        float4 q;
        q.x = w[k4.x * NC + c];
        q.y = w[k4.y * NC + c];
        q.z = w[k4.z * NC + c];
        q.w = w[k4.w * NC + c];
        float d;
        d = q.x - zq.x; lsum = fmaf(d, d, lsum);
        d = q.y - zq.y; lsum = fmaf(d, d, lsum);
        d = q.z - zq.z; lsum = fmaf(d, d, lsum);
        d = q.w - zq.w; lsum = fmaf(d, d, lsum);
        *(float4*)(ob + (size_t)c * NHW + hw4) = q;
    }
#pragma unroll
    for (int off = 32; off; off >>= 1) lsum += __shfl_down(lsum, off, 64);
    const int lane = tid & 63, wv = tid >> 6;
    if (lane == 0) lred[wv] = lsum;
    __syncthreads();
    if (tid == 0)
        atomicAdd(loss_sum, lred[0] + lred[1] + lred[2] + lred[3]);
}

// ---------------- K4: finalize loss + perplexity ----------------
__global__ __launch_bounds__(256) void vq_final(const unsigned int* __restrict__ counts,
                                                const float* __restrict__ loss_sum,
                                                float* __restrict__ out) {
    __shared__ float red[4];
    const int tid = threadIdx.x;
    float s = 0.f;
#pragma unroll
    for (int p = 0; p < 4; ++p) {
        const float pr = (float)counts[tid + p * 256] * (1.f / 32768.f);
        s = fmaf(pr, logf(pr + 1e-10f), s);
    }
#pragma unroll
    for (int off = 32; off; off >>= 1) s += __shfl_down(s, off, 64);
    if ((tid & 63) == 0) red[tid >> 6] = s;
    __syncthreads();
    if (tid == 0) {
        const float tot = red[0] + red[1] + red[2] + red[3];
        out[NELEM]     = loss_sum[0] * (1.25f / (float)NELEM);
        out[NELEM + 1] = expf(-tot);
    }
}

extern "C" void kernel_launch(void* const* d_in, const int* in_sizes, int n_in,
                              void* d_out, int out_size, void* d_ws, size_t ws_size,
                              hipStream_t stream) {
    const float* z = (const float*)d_in[0];
    const float* w = (const float*)d_in[1];
    float* out = (float*)d_out;

    float*          wsq      = (float*)d_ws;
    unsigned int*   counts   = (unsigned int*)((char*)d_ws + 4096);
    float*          loss_sum = (float*)((char*)d_ws + 8192);
    unsigned short* cbfrag   = (unsigned short*)((char*)d_ws + 16384);   // 512 KB
    int*            gfidx    = (int*)((char*)d_ws + 540672);             // 128 KB
    // zfrag scratch: first 16 MB of OUT (guaranteed 33.5 MB); scatter
    // overwrites the whole buffer afterward in stream order.
    unsigned short* zfrag    = (unsigned short*)out;

    vq_prep   <<<64,   256, 0, stream>>>(w, cbfrag, wsq, counts, loss_sum);
    vq_zpack  <<<512,  256, 0, stream>>>(z, zfrag);
    vq_dist   <<<512,  256, 0, stream>>>(zfrag, wsq, cbfrag, counts, gfidx);
    vq_scatter<<<1024, 256, 0, stream>>>(z, w, gfidx, loss_sum, out);
    vq_final  <<<1,    256, 0, stream>>>(counts, loss_sum, out);
}

// Round 7
// 115.306 us; speedup vs baseline: 1.2524x; 1.2524x over previous
//
#include <hip/hip_runtime.h>
#include <float.h>
#include <math.h>
#include <stdint.h>

// VQ-VAE VectorQuantizer — round 9: r1 skeleton + ping-pong cb prefetch.
//
// z_e: (32, 256, 32, 32) fp32, weight: (1024, 256) fp32
// outputs concat: quantized_st (8388608) + loss (1) + perplexity (1)
//
// Attribution so far: fused main ~51 us = frag assembly ~12 + mt sweep ~40.
// mt sweep defies throughput math (MFMA 2.5 us, cb@L2 7 us) -> theory: the
// per-cc load->MFMA dependency serializes at L2/HBM latency (128 loads x
// ~300-900 cy exposed), and lockstep waves can't cover it (r5 occupancy-null).
// Round 9 = round-1 code (best measured, 123.2 us total) with ONE change:
// the mt loop is unrolled x2 into a ping-pong — mt+1's 8 cb loads issue
// into named regs B while mt's 32 MFMAs + compares run on regs A, so the
// vmcnt wait for B sits behind ~300+ cy of independent work. Same mt/cc/nt/r
// order -> bit-identical results.
//
// score[k][n] = wsq[k] - 2*w_k.z_n  via  mfma_f32_16x16x32_bf16:
//   A (M=16 codes)  = -2*w  (bf16, A-frag order, streamed from L2)
//   B (N=16 z vecs) =  z    (bf16, register-resident, 4 N-tiles = 64 z/wave)
//   C init          =  wsq[k]
//
// ws layout (bytes): [0,4096) wsq f32 | [4096,8192) counts u32
//                    [8192,8196) loss_sum f32 | [16384, 16384+524288) cbfrag

#define NB   32
#define NC   256
#define NHW  1024
#define NK   1024
#define NELEM (NB*NC*NHW)   // 8388608

typedef __attribute__((ext_vector_type(8))) short bf16x8;   // 8 bf16 = 4 VGPRs
typedef __attribute__((ext_vector_type(4))) float f32x4;

__device__ __forceinline__ unsigned short f2bf(float f) {   // RTN fp32->bf16
    unsigned u = __float_as_uint(f);
    u += 0x7FFFu + ((u >> 16) & 1u);
    return (unsigned short)(u >> 16);
}

// ---------------- K1: prep — pack A-frags (-2w bf16) + wsq + zero accums ---
__global__ __launch_bounds__(256) void vq_prep(const float* __restrict__ w,
                                               unsigned short* __restrict__ cb,
                                               float* __restrict__ wsq,
                                               unsigned int* __restrict__ counts,
                                               float* __restrict__ loss_sum) {
    __shared__ float swsq[4][16];
    const int t   = blockIdx.x;          // code tile 0..63 (16 codes each)
    const int tid = threadIdx.x;
    float sq = 0.f;
#pragma unroll
    for (int rep = 0; rep < 2; ++rep) {
        const int p = tid + rep * 256;   // 0..511
        const int cc = p >> 6, l = p & 63;
        const int n = l & 15, quad = l >> 4;
        const float* src = w + (t * 16 + n) * NC + cc * 32 + quad * 8;
        const float4 f0 = *(const float4*)src;
        const float4 f1 = *(const float4*)(src + 4);
        union { unsigned short u[8]; uint4 v; } pk;
        pk.u[0] = f2bf(-2.f * f0.x); pk.u[1] = f2bf(-2.f * f0.y);
        pk.u[2] = f2bf(-2.f * f0.z); pk.u[3] = f2bf(-2.f * f0.w);
        pk.u[4] = f2bf(-2.f * f1.x); pk.u[5] = f2bf(-2.f * f1.y);
        pk.u[6] = f2bf(-2.f * f1.z); pk.u[7] = f2bf(-2.f * f1.w);
        *(uint4*)(cb + (size_t)t * 4096 + cc * 512 + l * 8) = pk.v;
        sq = fmaf(f0.x, f0.x, sq); sq = fmaf(f0.y, f0.y, sq);
        sq = fmaf(f0.z, f0.z, sq); sq = fmaf(f0.w, f0.w, sq);
        sq = fmaf(f1.x, f1.x, sq); sq = fmaf(f1.y, f1.y, sq);
        sq = fmaf(f1.z, f1.z, sq); sq = fmaf(f1.w, f1.w, sq);
    }
    sq += __shfl_xor(sq, 16, 64);
    sq += __shfl_xor(sq, 32, 64);
    const int wv = tid >> 6, lane = tid & 63;
    if (lane < 16) swsq[wv][lane] = sq;
    __syncthreads();
    if (tid < 16)
        wsq[t * 16 + tid] = swsq[0][tid] + swsq[1][tid] + swsq[2][tid] + swsq[3][tid];
    if (t == 0) {
        for (int i = tid; i < NK; i += 256) counts[i] = 0u;
        if (tid == 0) loss_sum[0] = 0.f;
    }
}

// ---------------- K2: main — MFMA argmin (prefetched) + gather + loss ------
// grid 512 x 256 (4 waves). Block: 64 z vecs (b = bid>>4, hw0 = (bid&15)*64).
// Wave wv owns code quarter [wv*256, wv*256+256).
__global__ __launch_bounds__(256, 2) void vq_main7(const float* __restrict__ z,
                                                   const float* __restrict__ w,
                                                   const float* __restrict__ wsq,
                                                   const unsigned short* __restrict__ cb,
                                                   unsigned int* __restrict__ counts,
                                                   float* __restrict__ loss_sum,
                                                   float* __restrict__ out) {
    __shared__ float sval[4][64];
    __shared__ int   sidx[4][64];
    __shared__ int   fidx[64];
    __shared__ float lred[4];

    const int tid  = threadIdx.x;
    const int wv   = tid >> 6;            // code quarter 0..3
    const int lane = tid & 63;
    const int n    = lane & 15;
    const int quad = lane >> 4;
    const int bid  = blockIdx.x;
    const int b    = bid >> 4;            // batch image
    const int hw0  = (bid & 15) << 6;     // block's 64-row hw origin

    const float* zb = z + (size_t)b * (NC * NHW);

    // ---- Phase A: 64 z vectors -> register B-fragments (bf16) -------------
    bf16x8 bfr[4][8];
#pragma unroll
    for (int nt = 0; nt < 4; ++nt) {
#pragma unroll
        for (int cc = 0; cc < 8; ++cc) {
            const float* zp = zb + (size_t)(cc * 32 + quad * 8) * NHW + hw0 + nt * 16 + n;
            union { unsigned short u[8]; bf16x8 v; } pk;
#pragma unroll
            for (int j = 0; j < 8; ++j) pk.u[j] = f2bf(zp[(size_t)j * NHW]);
            bfr[nt][cc] = pk.v;
        }
    }

    // ---- Main loop: ping-pong prefetch of cb tiles ------------------------
    float bv[4] = {FLT_MAX, FLT_MAX, FLT_MAX, FLT_MAX};
    int   bi[4] = {0, 0, 0, 0};
    const unsigned short* ap0 = cb + (size_t)(wv * 16) * 4096 + lane * 8;

    bf16x8 pa[8], pb[8];
#pragma unroll
    for (int cc = 0; cc < 8; ++cc) pa[cc] = *(const bf16x8*)(ap0 + cc * 512);

#define MT_BODY(MT, CUR, NXT, PREF)                                            \
    {                                                                          \
        if (PREF) {                                                            \
            const unsigned short* apn = ap0 + (size_t)((MT) + 1) * 4096;       \
            _Pragma("unroll")                                                  \
            for (int cc = 0; cc < 8; ++cc)                                     \
                NXT[cc] = *(const bf16x8*)(apn + cc * 512);                    \
        }                                                                      \
        const int kt = wv * 256 + (MT) * 16;                                   \
        const f32x4 w4 = *(const f32x4*)(wsq + kt + quad * 4);                 \
        f32x4 acc[4];                                                          \
        _Pragma("unroll")                                                      \
        for (int nt = 0; nt < 4; ++nt) acc[nt] = w4;                           \
        _Pragma("unroll")                                                      \
        for (int cc = 0; cc < 8; ++cc) {                                       \
            acc[0] = __builtin_amdgcn_mfma_f32_16x16x32_bf16(CUR[cc], bfr[0][cc], acc[0], 0, 0, 0); \
            acc[1] = __builtin_amdgcn_mfma_f32_16x16x32_bf16(CUR[cc], bfr[1][cc], acc[1], 0, 0, 0); \
            acc[2] = __builtin_amdgcn_mfma_f32_16x16x32_bf16(CUR[cc], bfr[2][cc], acc[2], 0, 0, 0); \
            acc[3] = __builtin_amdgcn_mfma_f32_16x16x32_bf16(CUR[cc], bfr[3][cc], acc[3], 0, 0, 0); \
        }                                                                      \
        _Pragma("unroll")                                                      \
        for (int nt = 0; nt < 4; ++nt) {                                       \
            _Pragma("unroll")                                                  \
            for (int r = 0; r < 4; ++r) {                                      \
                const float v = acc[nt][r];                                    \
                if (v < bv[nt]) { bv[nt] = v; bi[nt] = kt + quad * 4 + r; }    \
            }                                                                  \
        }                                                                      \
    }

    for (int mt2 = 0; mt2 < 8; ++mt2) {
        const int mt = mt2 * 2;
        MT_BODY(mt,     pa, pb, true);
        MT_BODY(mt + 1, pb, pa, (mt2 < 7));
    }
#undef MT_BODY

    // ---- cross-quad argmin (lanes n, n+16, n+32, n+48) --------------------
#pragma unroll
    for (int nt = 0; nt < 4; ++nt) {
#pragma unroll
        for (int off = 16; off <= 32; off <<= 1) {
            const float ov = __shfl_xor(bv[nt], off, 64);
            const int   ok = __shfl_xor(bi[nt], off, 64);
            if (ov < bv[nt] || (ov == bv[nt] && ok < bi[nt])) { bv[nt] = ov; bi[nt] = ok; }
        }
    }
    if (lane < 16) {
#pragma unroll
        for (int nt = 0; nt < 4; ++nt) {
            sval[wv][nt * 16 + lane] = bv[nt];
            sidx[wv][nt * 16 + lane] = bi[nt];
        }
    }
    __syncthreads();

    // ---- cross-wave argmin over the 4 code quarters -----------------------
    if (tid < 64) {
        float bestv = sval[0][tid];
        int   besti = sidx[0][tid];
#pragma unroll
        for (int q = 1; q < 4; ++q) {
            const float v = sval[q][tid];
            const int   k = sidx[q][tid];
            if (v < bestv || (v == bestv && k < besti)) { bestv = v; besti = k; }
        }
        fidx[tid] = besti;
        atomicAdd(&counts[besti], 1u);
    }
    __syncthreads();

    // ---- Phase 2: gather codebook rows, write quantized, accumulate loss --
    float lsum = 0.f;
    const int hwl = tid & 63;
    const int cg  = tid >> 6;             // 0..3 -> c range [cg*64, cg*64+64)
    const int myk = fidx[hwl];
    const float* wr  = w + myk * NC;
    const float* zp2 = zb + hw0 + hwl;
    float*       op  = out + (size_t)b * (NC * NHW) + hw0 + hwl;
#pragma unroll 4
    for (int p = 0; p < 16; ++p) {
        const int c0 = cg * 64 + p * 4;
        const float4 q4 = *(const float4*)(wr + c0);
        const float qa[4] = {q4.x, q4.y, q4.z, q4.w};
#pragma unroll
        for (int u = 0; u < 4; ++u) {
            const int c = c0 + u;
            const float zv = zp2[(size_t)c * NHW];
            const float d = qa[u] - zv;
            lsum = fmaf(d, d, lsum);
            op[(size_t)c * NHW] = qa[u];
        }
    }
#pragma unroll
    for (int off = 32; off; off >>= 1) lsum += __shfl_down(lsum, off, 64);
    if (lane == 0) lred[wv] = lsum;
    __syncthreads();
    if (tid == 0)
        atomicAdd(loss_sum, lred[0] + lred[1] + lred[2] + lred[3]);
}

// ---------------- K3: finalize loss + perplexity ----------------
__global__ __launch_bounds__(256) void vq_final(const unsigned int* __restrict__ counts,
                                                const float* __restrict__ loss_sum,
                                                float* __restrict__ out) {
    __shared__ float red[4];
    const int tid = threadIdx.x;
    float s = 0.f;
#pragma unroll
    for (int p = 0; p < 4; ++p) {
        const float pr = (float)counts[tid + p * 256] * (1.f / 32768.f);
        s = fmaf(pr, logf(pr + 1e-10f), s);
    }
#pragma unroll
    for (int off = 32; off; off >>= 1) s += __shfl_down(s, off, 64);
    if ((tid & 63) == 0) red[tid >> 6] = s;
    __syncthreads();
    if (tid == 0) {
        const float tot = red[0] + red[1] + red[2] + red[3];
        out[NELEM]     = loss_sum[0] * (1.25f / (float)NELEM);
        out[NELEM + 1] = expf(-tot);
    }
}

extern "C" void kernel_launch(void* const* d_in, const int* in_sizes, int n_in,
                              void* d_out, int out_size, void* d_ws, size_t ws_size,
                              hipStream_t stream) {
    const float* z = (const float*)d_in[0];
    const float* w = (const float*)d_in[1];
    float* out = (float*)d_out;

    float*          wsq      = (float*)d_ws;
    unsigned int*   counts   = (unsigned int*)((char*)d_ws + 4096);
    float*          loss_sum = (float*)((char*)d_ws + 8192);
    unsigned short* cbfrag   = (unsigned short*)((char*)d_ws + 16384);  // 512 KB

    vq_prep <<<64,  256, 0, stream>>>(w, cbfrag, wsq, counts, loss_sum);
    vq_main7<<<512, 256, 0, stream>>>(z, w, wsq, cbfrag, counts, loss_sum, out);
    vq_final<<<1,   256, 0, stream>>>(counts, loss_sum, out);
}